// Round 11
// baseline (220.279 us; speedup 1.0000x reference)
//
#include <hip/hip_runtime.h>
#include <math.h>

// CapsuleLayer dynamic routing, fused. R11: i-parity-split lane mapping.
// Ledger: 64-VGPR cap immovable (R2/R3/R6/R7/R9); W-through-LDS is net
// negative (R10: LDS pipe + 18 barriers + 1.2e7 conflicts -> 127 us).
// R8 (88 us) = TA wall (16x64B segments/W-inst, ~43 us) + L2 delivery
// (5.9 MB/CU, ~44 us). This round removes half the TA wall for free:
// lane = rl*8 + i2*4 + og; lane accumulates the i===i2 (mod 2) half of
// row r = wid*72 + p*8 + rl. A W wave-load then covers 8 rows x 128 B
// CONTIGUOUS (full lines) = 8 segments/inst vs R8's 16. No LDS staging,
// no Phase-A barriers, same minimal FMA count. pri[9]=36 regs (R8-proven).
// One shfl_xor(4) fold per pri[p] at Phase-A end merges the i2 halves.
// LDS ~5.7 KB -> 2 blocks/CU x 1024 thr = 32 waves = 100% occupancy.
// c-major blocks: 256 consecutive blocks share W[c] (589 KB) in L2.

#define NC 10
#define NR 1152
#define IC 8
#define OC 16
#define NITER 3
#define T 1024

__global__ __launch_bounds__(T) void caps_route(
    const float* __restrict__ x,   // [B, NR, IC]
    const float* __restrict__ W,   // [NC, NR, IC, OC]
    float* __restrict__ out)       // [B, NC, OC]
{
    __shared__ float logit[NR];    // collapsed logits (broadcast over OC)
    __shared__ float redm[16];     // per-wave softmax stats
    __shared__ float sred[256];    // [16 waves][16 o] s partials
    __shared__ float vout[OC];     // current output vector

    const int t    = threadIdx.x;
    const int lane = t & 63;
    const int wid  = t >> 6;          // 0..15
    const int og   = lane & 3;        // o-quad (o = og*4+j)
    const int i2   = (lane >> 2) & 1; // i-parity owned by this lane
    const int rl   = lane >> 3;       // 0..7: row-local within wave
    const int rbase = wid * 72 + rl;  // row = rbase + p*8, p in 0..8

    const int c = blockIdx.x >> 8;    // c-major: 256 consecutive blocks share W[c]
    const int b = blockIdx.x & 255;

    const float4* __restrict__ xb = (const float4*)(x + (size_t)b * (NR * IC));
    const float4* __restrict__ wb = (const float4*)(W + (size_t)c * (NR * IC * OC));

    // ---------------- Phase A: half-dot priors ------------------------------
    // Lane loads W[r, i2+2j, og-quad] (j=0..3): per inst the wave covers
    // 8 consecutive rows x 128 B contiguous -> 8 full-line segments.
    float4 pri[9];
#pragma unroll
    for (int p = 0; p < 9; ++p) {
        const int r = rbase + (p << 3);
        float4 xa = xb[2 * r];
        float4 xc = xb[2 * r + 1];
        const float4* wp = wb + (size_t)r * 32 + i2 * 4 + og;
        float4 w0 = wp[0], w1 = wp[8], w2 = wp[16], w3 = wp[24];
        // x components of parity i2: i = i2, i2+2, i2+4, i2+6
        float x0 = i2 ? xa.y : xa.x;
        float x1 = i2 ? xa.w : xa.z;
        float x2 = i2 ? xc.y : xc.x;
        float x3 = i2 ? xc.w : xc.z;
        float4 acc;
        acc.x = x0 * w0.x; acc.y = x0 * w0.y; acc.z = x0 * w0.z; acc.w = x0 * w0.w;
        acc.x = fmaf(x1, w1.x, acc.x); acc.y = fmaf(x1, w1.y, acc.y);
        acc.z = fmaf(x1, w1.z, acc.z); acc.w = fmaf(x1, w1.w, acc.w);
        acc.x = fmaf(x2, w2.x, acc.x); acc.y = fmaf(x2, w2.y, acc.y);
        acc.z = fmaf(x2, w2.z, acc.z); acc.w = fmaf(x2, w2.w, acc.w);
        acc.x = fmaf(x3, w3.x, acc.x); acc.y = fmaf(x3, w3.y, acc.y);
        acc.z = fmaf(x3, w3.z, acc.z); acc.w = fmaf(x3, w3.w, acc.w);
        pri[p] = acc;
    }
    // merge the two i-parity halves: lanes lane^4 hold the complement
#pragma unroll
    for (int p = 0; p < 9; ++p) {
        pri[p].x += __shfl_xor(pri[p].x, 4, 64);
        pri[p].y += __shfl_xor(pri[p].y, 4, 64);
        pri[p].z += __shfl_xor(pri[p].z, 4, 64);
        pri[p].w += __shfl_xor(pri[p].w, 4, 64);
    }

    // ---------------- Phase B: 3 routing iterations -------------------------
    for (int it = 0; it < NITER; ++it) {
        const bool uni = (it == 0);   // softmax of zeros = uniform
        float m = 0.f, invd = 0.f;
        if (!uni) {
            float l0 = logit[t];      // t covers 0..1023
            float lt = 0.f;
            float lm = l0;
            if (t < 128) { lt = logit[1024 + t]; lm = fmaxf(lm, lt); }
#pragma unroll
            for (int msk = 1; msk <= 32; msk <<= 1)
                lm = fmaxf(lm, __shfl_xor(lm, msk, 64));
            if (lane == 0) redm[wid] = lm;
            __syncthreads();
            m = redm[0];
#pragma unroll
            for (int w = 1; w < 16; ++w) m = fmaxf(m, redm[w]);
            float e = __expf(l0 - m);
            if (t < 128) e += __expf(lt - m);
#pragma unroll
            for (int msk = 1; msk <= 32; msk <<= 1)
                e += __shfl_xor(e, msk, 64);
            __syncthreads();          // m reads done before redm rewrite
            if (lane == 0) redm[wid] = e;
            __syncthreads();
            float den = redm[0];
#pragma unroll
            for (int w = 1; w < 16; ++w) den += redm[w];
            invd = 1.f / den;
        }

        // s[o] partial = sum over owned rows of probs[r]*pri[r][o]
        float4 s4 = make_float4(0.f, 0.f, 0.f, 0.f);
#pragma unroll
        for (int p = 0; p < 9; ++p) {
            float wgt = 1.0f;
            if (!uni) wgt = __expf(logit[rbase + (p << 3)] - m);
            s4.x = fmaf(wgt, pri[p].x, s4.x);
            s4.y = fmaf(wgt, pri[p].y, s4.y);
            s4.z = fmaf(wgt, pri[p].z, s4.z);
            s4.w = fmaf(wgt, pri[p].w, s4.w);
        }
        // reduce over the 8 rl slots (masks 8,16,32); i2 pairs are duplicates
#pragma unroll
        for (int msk = 8; msk <= 32; msk <<= 1) {
            s4.x += __shfl_xor(s4.x, msk, 64);
            s4.y += __shfl_xor(s4.y, msk, 64);
            s4.z += __shfl_xor(s4.z, msk, 64);
            s4.w += __shfl_xor(s4.w, msk, 64);
        }
        __syncthreads();              // stats/prev-sred reads done
        if (lane < 4)                 // rl=0, i2=0, og=lane
            ((float4*)sred)[wid * 4 + og] = s4;   // sred[wid*16 + o]
        __syncthreads();

        if (t < OC) {                 // 16 threads of wave 0
            float s = 0.f;
#pragma unroll
            for (int w = 0; w < 16; ++w) s += sred[w * 16 + t];
            s *= uni ? (1.0f / 1152.0f) : invd;
            float sq = s * s;
#pragma unroll
            for (int msk = 1; msk <= 8; msk <<= 1) sq += __shfl_xor(sq, msk, 64);
            float v = s * (sqrtf(sq) / (1.0f + sq));   // squash
            if (it == NITER - 1) out[((size_t)b * NC + c) * OC + t] = v;
            else vout[t] = v;
        }
        __syncthreads();

        if (it < NITER - 1) {
            // logit[r] += sum_o pri[r][o]*v[o]
            float4 v4 = ((const float4*)vout)[og];
#pragma unroll
            for (int p = 0; p < 9; ++p) {
                float d = pri[p].x * v4.x + pri[p].y * v4.y +
                          pri[p].z * v4.z + pri[p].w * v4.w;
                d += __shfl_xor(d, 1, 64);   // fold og
                d += __shfl_xor(d, 2, 64);
                if (og == 0 && i2 == 0) {    // one writer per row
                    const int r = rbase + (p << 3);
                    if (it == 0) logit[r] = d;   // logits start at zero
                    else         logit[r] += d;
                }
            }
            __syncthreads();
        }
    }
}

extern "C" void kernel_launch(void* const* d_in, const int* in_sizes, int n_in,
                              void* d_out, int out_size, void* d_ws, size_t ws_size,
                              hipStream_t stream) {
    const float* x = (const float*)d_in[0];
    const float* W = (const float*)d_in[1];
    float* out = (float*)d_out;
    caps_route<<<dim3(NC * 256), dim3(T), 0, stream>>>(x, W, out);
}